// Round 1
// 1377.914 us; speedup vs baseline: 1.1839x; 1.1839x over previous
//
#include <hip/hip_runtime.h>
#include <hip/hip_bf16.h>
#include <math.h>

// Problem dims (compile-time)
constexpr int NB = 64;     // batch
constexpr int NT = 30;     // decode steps
constexpr int NS = 31;     // encoder positions
constexpr int NE = 128;    // embedding dim
constexpr int NU = 256;    // hidden
constexpr int NV = 32000;  // vocab
constexpr int NG = 4 * NU;    // 1024 (gates)
constexpr int NCIN = NE + NU; // 384

__device__ __forceinline__ float sigmoidf_(float x) {
    return 1.0f / (1.0f + __expf(-x));
}

// ---------------------------------------------------------------------------
// keys[b,s,v] = sum_u memory[b,s,u] * W_mem[u,v]
// ---------------------------------------------------------------------------
__global__ __launch_bounds__(256) void keys_kernel(
    const float* __restrict__ memory, const float* __restrict__ W_mem,
    float* __restrict__ keys) {
    const int row0 = blockIdx.x * 8;
    const int u = threadIdx.x;
    __shared__ float mS[8][NU];
#pragma unroll
    for (int r = 0; r < 8; ++r) mS[r][u] = memory[(row0 + r) * NU + u];
    __syncthreads();
    float acc[8] = {0, 0, 0, 0, 0, 0, 0, 0};
#pragma unroll 4
    for (int v = 0; v < NU; ++v) {
        float w = W_mem[v * NU + u];
#pragma unroll
        for (int r = 0; r < 8; ++r) acc[r] += mS[r][v] * w;
    }
#pragma unroll
    for (int r = 0; r < 8; ++r) keys[(row0 + r) * NU + u] = acc[r];
}

// ---------------------------------------------------------------------------
// Recurrence: one block of 1024 threads per batch element (16 waves/CU =
// 4 waves/SIMD; v1 ran 1 wave/SIMD and was ~80% vmcnt-stalled on L2-resident
// weight loads). All long k-loops split 4 ways over p = tid>>8:
//   z-phase : p owns W_k rows [96p,96p+96) and W_r rows [64p,64p+64)
//   attn    : p owns concat(h,ctx) rows [128p,128p+128)
// Partials reduced through LDS. memory[b] staged in LDS once (31 KB).
// ---------------------------------------------------------------------------
__global__ __launch_bounds__(1024) void recurrence_kernel(
    const int* __restrict__ inputs,
    const float* __restrict__ memory,
    const float* __restrict__ sample_h,
    const float* __restrict__ sample_c,
    const float* __restrict__ emb,
    const float* __restrict__ W_k,
    const float* __restrict__ W_r,
    const float* __restrict__ b_lstm,
    const float* __restrict__ W_attn,
    const float* __restrict__ keys,
    float* __restrict__ attn_all)
{
    const int b = blockIdx.x;
    const int tid = threadIdx.x;

    __shared__ float memS[NS * NU];   // 31.0 KB
    __shared__ float zPart[4 * NG];   // 16.0 KB (reused as attn partials)
    __shared__ float cinS[NCIN];
    __shared__ float hS[NU];
    __shared__ float ctxS[NU];
    __shared__ float attnS[NU];
    __shared__ float scS[32];

    const float* keysb = keys + (size_t)b * NS * NU;
    const float* memb  = memory + (size_t)b * NS * NU;

    for (int i = tid; i < NS * NU / 4; i += 1024)
        ((float4*)memS)[i] = ((const float4*)memb)[i];

    float c_reg = 0.0f;
    if (tid < NU) {
        c_reg = sample_c[b * NU + tid];
        hS[tid] = sample_h[b * NU + tid];
        attnS[tid] = 0.0f;
    }

    const int cg = tid & 255;   // column group (z: columns 4cg..4cg+3; attn: u=cg)
    const int p  = tid >> 8;    // k-partition 0..3 (wave-uniform)
    const float* Wk_p = W_k + (size_t)(p * 96) * NG + cg * 4;
    const float* Wr_p = W_r + (size_t)(p * 64) * NG + cg * 4;
    float4 bias4;
    {
        const float4 bv = *(const float4*)(b_lstm + cg * 4);
        bias4 = (p == 0) ? bv : make_float4(0.f, 0.f, 0.f, 0.f);
    }
    const float* Wa_p = W_attn + (size_t)(p * 128) * NU + cg;

    __syncthreads();

    for (int t = 0; t < NT; ++t) {
        // --- P1: cell_in = concat(x_t, attn_{t-1}) ---
        if (tid < NE) {
            int idx = inputs[b * NT + t];
            cinS[tid] = emb[(size_t)idx * NE + tid];
        } else if (tid < NCIN) {
            cinS[tid] = attnS[tid - NE];
        }
        __syncthreads();

        // --- P2: z partials ---
        {
            float4 acc = bias4;
            const float* cp = cinS + p * 96;
#pragma unroll 8
            for (int k = 0; k < 96; ++k) {
                float a = cp[k];
                float4 w = *(const float4*)(Wk_p + (size_t)k * NG);
                acc.x += a * w.x; acc.y += a * w.y;
                acc.z += a * w.z; acc.w += a * w.w;
            }
            const float* hp = hS + p * 64;
#pragma unroll 8
            for (int k = 0; k < 64; ++k) {
                float a = hp[k];
                float4 w = *(const float4*)(Wr_p + (size_t)k * NG);
                acc.x += a * w.x; acc.y += a * w.y;
                acc.z += a * w.z; acc.w += a * w.w;
            }
            *(float4*)(zPart + p * NG + cg * 4) = acc;
        }
        __syncthreads();

        // --- P3: reduce + LSTM gates ---
        if (tid < NU) {
            float zi = 0.f, zf = 0.f, zg = 0.f, zo = 0.f;
#pragma unroll
            for (int q = 0; q < 4; ++q) {
                zi += zPart[q * NG + tid];
                zf += zPart[q * NG + NU + tid];
                zg += zPart[q * NG + 2 * NU + tid];
                zo += zPart[q * NG + 3 * NU + tid];
            }
            c_reg = sigmoidf_(zf) * c_reg + sigmoidf_(zi) * tanhf(zg);
            hS[tid] = sigmoidf_(zo) * tanhf(c_reg);
        }
        __syncthreads();

        // --- P4: score[s] = h . keys[b,s,:]; one 32-lane group per s ---
        {
            const int s = tid >> 5, j = tid & 31;
            if (s < NS) {
                float sp = 0.0f;
#pragma unroll
                for (int i = 0; i < 8; ++i)
                    sp += hS[i * 32 + j] * keysb[s * NU + i * 32 + j];
#pragma unroll
                for (int m = 16; m; m >>= 1) sp += __shfl_xor(sp, m, 32);
                if (j == 0) scS[s] = sp;
            }
        }
        __syncthreads();

        // --- P5: softmax + context (LDS-only reads) ---
        if (tid < NU) {
            float mx = scS[0];
#pragma unroll
            for (int s = 1; s < NS; ++s) mx = fmaxf(mx, scS[s]);
            float sumE = 0.0f, ctx = 0.0f;
#pragma unroll 4
            for (int s = 0; s < NS; ++s) {
                float e = __expf(scS[s] - mx);
                sumE += e;
                ctx += e * memS[s * NU + tid];
            }
            ctxS[tid] = ctx / sumE;
        }
        __syncthreads();

        // --- P6: attn partials = concat(h, ctx)[pk] @ W_attn[pk, :] ---
        {
            const float* src = (p < 2) ? (hS + p * 128) : (ctxS + (p - 2) * 128);
            float aa = 0.0f;
#pragma unroll 8
            for (int i = 0; i < 128; ++i)
                aa += src[i] * Wa_p[(size_t)i * NU];
            zPart[p * NU + cg] = aa;
        }
        __syncthreads();

        // --- P6b: reduce + write attn ---
        if (tid < NU) {
            float a = zPart[tid] + zPart[NU + tid] +
                      zPart[2 * NU + tid] + zPart[3 * NU + tid];
            attnS[tid] = a;
            attn_all[((size_t)b * NT + t) * NU + tid] = a;
        }
        __syncthreads();
    }
}

// ---------------------------------------------------------------------------
// out[m, n] = attn_all[m, :] @ W_fc[:, n] + b_fc[n]
// ---------------------------------------------------------------------------
constexpr int BM = 128, BN = 128, KC = 32, KTOT = NU;

__global__ __launch_bounds__(256) void out_gemm(
    const float* __restrict__ A,
    const float* __restrict__ Wfc,
    const float* __restrict__ bfc,
    float* __restrict__ out)
{
    const int n0 = blockIdx.x * BN;
    const int m0 = blockIdx.y * BM;
    const int tid = threadIdx.x;
    const int tx = tid & 15, ty = tid >> 4;

    __shared__ float As[KC][BM + 4];
    __shared__ float Bs[KC][BN];

    float acc[2][4][2][4] = {};

    const int kq = tid & 7,  r0 = tid >> 3;
    const int nq = tid & 31, kr0 = tid >> 5;

    for (int kb = 0; kb < KTOT; kb += KC) {
#pragma unroll
        for (int p = 0; p < 4; ++p) {
            int r = r0 + p * 32;
            float4 av = *(const float4*)(A + (size_t)(m0 + r) * KTOT + kb + kq * 4);
            As[kq * 4 + 0][r] = av.x;
            As[kq * 4 + 1][r] = av.y;
            As[kq * 4 + 2][r] = av.z;
            As[kq * 4 + 3][r] = av.w;
        }
#pragma unroll
        for (int p = 0; p < 4; ++p) {
            int kr = kr0 + p * 8;
            *(float4*)&Bs[kr][nq * 4] =
                *(const float4*)(Wfc + (size_t)(kb + kr) * NV + n0 + nq * 4);
        }
        __syncthreads();

#pragma unroll 4
        for (int k = 0; k < KC; ++k) {
            float4 a0 = *(const float4*)&As[k][ty * 4];
            float4 a1 = *(const float4*)&As[k][64 + ty * 4];
            float4 b0 = *(const float4*)&Bs[k][tx * 4];
            float4 b1 = *(const float4*)&Bs[k][64 + tx * 4];
            float am[2][4] = {{a0.x, a0.y, a0.z, a0.w}, {a1.x, a1.y, a1.z, a1.w}};
            float bv[2][4] = {{b0.x, b0.y, b0.z, b0.w}, {b1.x, b1.y, b1.z, b1.w}};
#pragma unroll
            for (int im = 0; im < 2; ++im)
#pragma unroll
                for (int i = 0; i < 4; ++i)
#pragma unroll
                    for (int jn = 0; jn < 2; ++jn)
#pragma unroll
                        for (int j = 0; j < 4; ++j)
                            acc[im][i][jn][j] += am[im][i] * bv[jn][j];
        }
        __syncthreads();
    }

    float4 bias[2];
    bias[0] = *(const float4*)(bfc + n0 + tx * 4);
    bias[1] = *(const float4*)(bfc + n0 + 64 + tx * 4);
#pragma unroll
    for (int im = 0; im < 2; ++im)
#pragma unroll
        for (int i = 0; i < 4; ++i) {
            int m = m0 + im * 64 + ty * 4 + i;
#pragma unroll
            for (int jn = 0; jn < 2; ++jn) {
                float4 v;
                float4 bb = bias[jn];
                v.x = acc[im][i][jn][0] + bb.x;
                v.y = acc[im][i][jn][1] + bb.y;
                v.z = acc[im][i][jn][2] + bb.z;
                v.w = acc[im][i][jn][3] + bb.w;
                *(float4*)(out + (size_t)m * NV + n0 + jn * 64 + tx * 4) = v;
            }
        }
}

// ---------------------------------------------------------------------------
extern "C" void kernel_launch(void* const* d_in, const int* in_sizes, int n_in,
                              void* d_out, int out_size, void* d_ws, size_t ws_size,
                              hipStream_t stream) {
    const int*   inputs   = (const int*)  d_in[0];
    const float* memory   = (const float*)d_in[1];
    const float* sample_h = (const float*)d_in[2];
    const float* sample_c = (const float*)d_in[3];
    const float* emb      = (const float*)d_in[4];
    const float* W_k      = (const float*)d_in[5];
    const float* W_r      = (const float*)d_in[6];
    const float* b_lstm   = (const float*)d_in[7];
    const float* W_mem    = (const float*)d_in[8];
    const float* W_attn   = (const float*)d_in[9];
    const float* W_fc     = (const float*)d_in[10];
    const float* b_fc     = (const float*)d_in[11];
    float* out = (float*)d_out;

    float* keys = (float*)d_ws;
    float* attn_all = keys + (size_t)NB * NS * NU;

    keys_kernel<<<(NB * NS) / 8, 256, 0, stream>>>(memory, W_mem, keys);
    recurrence_kernel<<<NB, 1024, 0, stream>>>(inputs, memory, sample_h, sample_c,
                                               emb, W_k, W_r, b_lstm, W_attn,
                                               keys, attn_all);
    out_gemm<<<dim3(NV / BN, (NB * NT) / BM), 256, 0, stream>>>(attn_all, W_fc,
                                                                b_fc, out);
}

// Round 2
// 1243.811 us; speedup vs baseline: 1.3115x; 1.1078x over previous
//
#include <hip/hip_runtime.h>
#include <hip/hip_bf16.h>
#include <math.h>

// Problem dims (compile-time)
constexpr int NB = 64;     // batch
constexpr int NT = 30;     // decode steps
constexpr int NS = 31;     // encoder positions
constexpr int NE = 128;    // embedding dim
constexpr int NU = 256;    // hidden
constexpr int NV = 32000;  // vocab
constexpr int NG = 4 * NU;    // 1024 (gates)

__device__ __forceinline__ float sigmoidf_(float x) {
    return 1.0f / (1.0f + __expf(-x));
}

// ---------------------------------------------------------------------------
// keys[b,s,v] = sum_u memory[b,s,u] * W_mem[u,v]
// ---------------------------------------------------------------------------
__global__ __launch_bounds__(256) void keys_kernel(
    const float* __restrict__ memory, const float* __restrict__ W_mem,
    float* __restrict__ keys) {
    const int row0 = blockIdx.x * 8;
    const int u = threadIdx.x;
    __shared__ float mS[8][NU];
#pragma unroll
    for (int r = 0; r < 8; ++r) mS[r][u] = memory[(row0 + r) * NU + u];
    __syncthreads();
    float acc[8] = {0, 0, 0, 0, 0, 0, 0, 0};
#pragma unroll 4
    for (int v = 0; v < NU; ++v) {
        float w = W_mem[v * NU + u];
#pragma unroll
        for (int r = 0; r < 8; ++r) acc[r] += mS[r][v] * w;
    }
#pragma unroll
    for (int r = 0; r < 8; ++r) keys[(row0 + r) * NU + u] = acc[r];
}

// ---------------------------------------------------------------------------
// Fused recurrent weights:
//   Wz[i][n] = sum_j W_attn[i][j] * W_k[128+j][n]  (+ W_r[i][n] if i<256)
// so that  z_t = z_emb + h@Wz[0:256] + ctx@Wz[256:512]   (t>0)
// This folds the per-step attention GEMM into the LSTM GEMM algebraically.
// ---------------------------------------------------------------------------
__global__ __launch_bounds__(256) void fuse_wz_kernel(
    const float* __restrict__ W_k,   // [384, NG]
    const float* __restrict__ W_r,   // [NU, NG]
    const float* __restrict__ W_a,   // [2*NU, NU]
    float* __restrict__ Wz)          // [2*NU, NG]
{
    const int col = blockIdx.x * 256 + threadIdx.x;
    const int rb = blockIdx.y * 8;
    __shared__ float waS[8][NU];
#pragma unroll
    for (int r = 0; r < 8; ++r) waS[r][threadIdx.x] = W_a[(size_t)(rb + r) * NU + threadIdx.x];
    __syncthreads();
    float acc[8] = {};
#pragma unroll 4
    for (int j = 0; j < NU; ++j) {
        float w = W_k[(size_t)(NE + j) * NG + col];
#pragma unroll
        for (int r = 0; r < 8; ++r) acc[r] += waS[r][j] * w;
    }
#pragma unroll
    for (int r = 0; r < 8; ++r) {
        int i = rb + r;
        float v = acc[r];
        if (i < NU) v += W_r[(size_t)i * NG + col];
        Wz[(size_t)i * NG + col] = v;
    }
}

// ---------------------------------------------------------------------------
// z_emb[m][n] = emb[inputs[m]] @ W_k[0:128] + b_lstm,  m = b*NT + t
// ---------------------------------------------------------------------------
__global__ __launch_bounds__(256) void zemb_kernel(
    const int* __restrict__ inputs, const float* __restrict__ emb,
    const float* __restrict__ W_k, const float* __restrict__ b_lstm,
    float* __restrict__ z_emb)
{
    const int col = blockIdx.x * 256 + threadIdx.x;
    const int m0 = blockIdx.y * 8;
    __shared__ float eS[8][NE];
    for (int i = threadIdx.x; i < 8 * NE; i += 256) {
        int r = i >> 7, e = i & 127;
        eS[r][e] = emb[(size_t)inputs[m0 + r] * NE + e];
    }
    __syncthreads();
    float acc[8] = {};
#pragma unroll 4
    for (int e = 0; e < NE; ++e) {
        float w = W_k[(size_t)e * NG + col];
#pragma unroll
        for (int r = 0; r < 8; ++r) acc[r] += eS[r][e] * w;
    }
    float bb = b_lstm[col];
#pragma unroll
    for (int r = 0; r < 8; ++r) z_emb[(size_t)(m0 + r) * NG + col] = acc[r] + bb;
}

// ---------------------------------------------------------------------------
// Recurrence: one block of 1024 threads per batch element, 4-way k-split.
// Fused form: z = z_emb[b,t] + h@Wz[0:256] + ctx@Wz[256:512] (t>0);
//             z = z_emb[b,0] + h0@W_r                        (t==0, attn0=0).
// Per step: 4 barriers, 2 MB of L2 weight reads (was 7 barriers / 3 MB).
// keys & memory staged in LDS once. Outputs h_all/ctx_all; attention layer
// and logits are applied by batched GEMMs afterwards.
// ---------------------------------------------------------------------------
__global__ __launch_bounds__(1024) void recurrence_kernel(
    const float* __restrict__ z_emb,     // [NB*NT, NG] (includes bias)
    const float* __restrict__ sample_h,
    const float* __restrict__ sample_c,
    const float* __restrict__ Wz,        // [2*NU, NG]
    const float* __restrict__ W_r,       // [NU, NG]
    const float* __restrict__ memory,    // [NB, NS, NU]
    const float* __restrict__ keys,      // [NB, NS, NU]
    float* __restrict__ h_all,           // [NB*NT, NU]
    float* __restrict__ ctx_all)         // [NB*NT, NU]
{
    const int b = blockIdx.x;
    const int tid = threadIdx.x;

    __shared__ float memS[NS * NU];   // 31 KB
    __shared__ float keyS[NS * NU];   // 31 KB
    __shared__ float zPart[4 * NG];   // 16 KB
    __shared__ float actS[2 * NU];    // [h | ctx]
    __shared__ float scS[32];

    const float* memb = memory + (size_t)b * NS * NU;
    const float* keyb = keys + (size_t)b * NS * NU;
    for (int i = tid; i < NS * NU / 4; i += 1024) {
        ((float4*)memS)[i] = ((const float4*)memb)[i];
        ((float4*)keyS)[i] = ((const float4*)keyb)[i];
    }

    float c_reg = 0.0f;
    if (tid < NU) {
        c_reg = sample_c[b * NU + tid];
        actS[tid] = sample_h[b * NU + tid];
    }

    const int cg = tid & 255;   // column quad (4 cols at cg*4)
    const int p  = tid >> 8;    // k-partition 0..3 (wave-uniform)
    const float* Wz_p = Wz + (size_t)(p * 128) * NG + cg * 4;
    const float* Wr_p = W_r + (size_t)(p * 64) * NG + cg * 4;
    const float* zerow = z_emb + ((size_t)b * NT) * NG + cg * 4;

    __syncthreads();

    for (int t = 0; t < NT; ++t) {
        // --- P2: z partials ---
        {
            float4 acc;
            if (p == 0) acc = *(const float4*)(zerow + (size_t)t * NG);
            else        acc = make_float4(0.f, 0.f, 0.f, 0.f);
            if (t == 0) {
                const float* ap = actS + p * 64;   // h only
#pragma unroll 8
                for (int k = 0; k < 64; ++k) {
                    float a = ap[k];
                    float4 w = *(const float4*)(Wr_p + (size_t)k * NG);
                    acc.x += a * w.x; acc.y += a * w.y;
                    acc.z += a * w.z; acc.w += a * w.w;
                }
            } else {
                const float* ap = actS + p * 128;  // [h|ctx]
#pragma unroll 16
                for (int k = 0; k < 128; ++k) {
                    float a = ap[k];
                    float4 w = *(const float4*)(Wz_p + (size_t)k * NG);
                    acc.x += a * w.x; acc.y += a * w.y;
                    acc.z += a * w.z; acc.w += a * w.w;
                }
            }
            *(float4*)(zPart + p * NG + cg * 4) = acc;
        }
        __syncthreads();

        // --- P3: reduce + LSTM gates ---
        if (tid < NU) {
            float zi = 0.f, zf = 0.f, zg = 0.f, zo = 0.f;
#pragma unroll
            for (int q = 0; q < 4; ++q) {
                zi += zPart[q * NG + tid];
                zf += zPart[q * NG + NU + tid];
                zg += zPart[q * NG + 2 * NU + tid];
                zo += zPart[q * NG + 3 * NU + tid];
            }
            c_reg = sigmoidf_(zf) * c_reg + sigmoidf_(zi) * tanhf(zg);
            float h = sigmoidf_(zo) * tanhf(c_reg);
            actS[tid] = h;
            h_all[((size_t)b * NT + t) * NU + tid] = h;
        }
        __syncthreads();

        // --- P4: score[s] = h . keys[b,s,:] (LDS), 32-lane group per s ---
        {
            const int s = tid >> 5, j = tid & 31;
            if (s < NS) {
                float sp = 0.0f;
#pragma unroll
                for (int i = 0; i < 8; ++i)
                    sp += actS[i * 32 + j] * keyS[s * NU + i * 32 + j];
#pragma unroll
                for (int m = 16; m; m >>= 1) sp += __shfl_xor(sp, m, 32);
                if (j == 0) scS[s] = sp;
            }
        }
        __syncthreads();

        // --- P5: softmax + context ---
        if (tid < NU) {
            float mx = scS[0];
#pragma unroll
            for (int s = 1; s < NS; ++s) mx = fmaxf(mx, scS[s]);
            float sumE = 0.0f, ctx = 0.0f;
#pragma unroll 4
            for (int s = 0; s < NS; ++s) {
                float e = __expf(scS[s] - mx);
                sumE += e;
                ctx += e * memS[s * NU + tid];
            }
            ctx /= sumE;
            actS[NU + tid] = ctx;
            ctx_all[((size_t)b * NT + t) * NU + tid] = ctx;
        }
        __syncthreads();
    }
}

// ---------------------------------------------------------------------------
// attn_all[m] = concat(h_all[m], ctx_all[m]) @ W_attn
// ---------------------------------------------------------------------------
__global__ __launch_bounds__(256) void attn_kernel(
    const float* __restrict__ h_all, const float* __restrict__ ctx_all,
    const float* __restrict__ W_a, float* __restrict__ attn_all)
{
    const int j = threadIdx.x;
    const int m0 = blockIdx.x * 8;
    __shared__ float hS[8][NU], cS[8][NU];
    for (int i = j; i < 8 * NU; i += 256) {
        int r = i >> 8, k = i & 255;
        hS[r][k] = h_all[(size_t)(m0 + r) * NU + k];
        cS[r][k] = ctx_all[(size_t)(m0 + r) * NU + k];
    }
    __syncthreads();
    float acc[8] = {};
#pragma unroll 2
    for (int k = 0; k < NU; ++k) {
        float w1 = W_a[(size_t)k * NU + j];
        float w2 = W_a[(size_t)(NU + k) * NU + j];
#pragma unroll
        for (int r = 0; r < 8; ++r) acc[r] += hS[r][k] * w1 + cS[r][k] * w2;
    }
#pragma unroll
    for (int r = 0; r < 8; ++r) attn_all[(size_t)(m0 + r) * NU + j] = acc[r];
}

// ---------------------------------------------------------------------------
// out[m, n] = attn_all[m, :] @ W_fc[:, n] + b_fc[n]
// Register double-buffered staging (issue-early / write-late) so global load
// latency hides under the 32-k compute phase.
// ---------------------------------------------------------------------------
constexpr int BM = 128, BN = 128, KC = 32, KTOT = NU;

__global__ __launch_bounds__(256) void out_gemm(
    const float* __restrict__ A,
    const float* __restrict__ Wfc,
    const float* __restrict__ bfc,
    float* __restrict__ out)
{
    const int n0 = blockIdx.x * BN;
    const int m0 = blockIdx.y * BM;
    const int tid = threadIdx.x;
    const int tx = tid & 15, ty = tid >> 4;

    __shared__ float As[KC][BM + 4];
    __shared__ float Bs[KC][BN];

    float acc[2][4][2][4] = {};

    const int kq = tid & 7,  r0 = tid >> 3;
    const int nq = tid & 31, kr0 = tid >> 5;

    float4 aR[4], bR[4];

    // prologue: stage chunk 0
#pragma unroll
    for (int p = 0; p < 4; ++p)
        aR[p] = *(const float4*)(A + (size_t)(m0 + r0 + p * 32) * KTOT + kq * 4);
#pragma unroll
    for (int p = 0; p < 4; ++p)
        bR[p] = *(const float4*)(Wfc + (size_t)(kr0 + p * 8) * NV + n0 + nq * 4);
#pragma unroll
    for (int p = 0; p < 4; ++p) {
        int r = r0 + p * 32;
        As[kq * 4 + 0][r] = aR[p].x;
        As[kq * 4 + 1][r] = aR[p].y;
        As[kq * 4 + 2][r] = aR[p].z;
        As[kq * 4 + 3][r] = aR[p].w;
        *(float4*)&Bs[kr0 + p * 8][nq * 4] = bR[p];
    }
    __syncthreads();

    for (int kb = 0; kb < KTOT; kb += KC) {
        const bool more = (kb + KC) < KTOT;
        if (more) {
#pragma unroll
            for (int p = 0; p < 4; ++p)
                aR[p] = *(const float4*)(A + (size_t)(m0 + r0 + p * 32) * KTOT + kb + KC + kq * 4);
#pragma unroll
            for (int p = 0; p < 4; ++p)
                bR[p] = *(const float4*)(Wfc + (size_t)(kb + KC + kr0 + p * 8) * NV + n0 + nq * 4);
        }

#pragma unroll 4
        for (int k = 0; k < KC; ++k) {
            float4 a0 = *(const float4*)&As[k][ty * 4];
            float4 a1 = *(const float4*)&As[k][64 + ty * 4];
            float4 b0 = *(const float4*)&Bs[k][tx * 4];
            float4 b1 = *(const float4*)&Bs[k][64 + tx * 4];
            float am[2][4] = {{a0.x, a0.y, a0.z, a0.w}, {a1.x, a1.y, a1.z, a1.w}};
            float bv[2][4] = {{b0.x, b0.y, b0.z, b0.w}, {b1.x, b1.y, b1.z, b1.w}};
#pragma unroll
            for (int im = 0; im < 2; ++im)
#pragma unroll
                for (int i = 0; i < 4; ++i)
#pragma unroll
                    for (int jn = 0; jn < 2; ++jn)
#pragma unroll
                        for (int j = 0; j < 4; ++j)
                            acc[im][i][jn][j] += am[im][i] * bv[jn][j];
        }
        __syncthreads();

        if (more) {
#pragma unroll
            for (int p = 0; p < 4; ++p) {
                int r = r0 + p * 32;
                As[kq * 4 + 0][r] = aR[p].x;
                As[kq * 4 + 1][r] = aR[p].y;
                As[kq * 4 + 2][r] = aR[p].z;
                As[kq * 4 + 3][r] = aR[p].w;
                *(float4*)&Bs[kr0 + p * 8][nq * 4] = bR[p];
            }
            __syncthreads();
        }
    }

    float4 bias[2];
    bias[0] = *(const float4*)(bfc + n0 + tx * 4);
    bias[1] = *(const float4*)(bfc + n0 + 64 + tx * 4);
#pragma unroll
    for (int im = 0; im < 2; ++im)
#pragma unroll
        for (int i = 0; i < 4; ++i) {
            int m = m0 + im * 64 + ty * 4 + i;
#pragma unroll
            for (int jn = 0; jn < 2; ++jn) {
                float4 v;
                float4 bb = bias[jn];
                v.x = acc[im][i][jn][0] + bb.x;
                v.y = acc[im][i][jn][1] + bb.y;
                v.z = acc[im][i][jn][2] + bb.z;
                v.w = acc[im][i][jn][3] + bb.w;
                *(float4*)(out + (size_t)m * NV + n0 + jn * 64 + tx * 4) = v;
            }
        }
}

// ---------------------------------------------------------------------------
extern "C" void kernel_launch(void* const* d_in, const int* in_sizes, int n_in,
                              void* d_out, int out_size, void* d_ws, size_t ws_size,
                              hipStream_t stream) {
    const int*   inputs   = (const int*)  d_in[0];
    const float* memory   = (const float*)d_in[1];
    const float* sample_h = (const float*)d_in[2];
    const float* sample_c = (const float*)d_in[3];
    const float* emb      = (const float*)d_in[4];
    const float* W_k      = (const float*)d_in[5];
    const float* W_r      = (const float*)d_in[6];
    const float* b_lstm   = (const float*)d_in[7];
    const float* W_mem    = (const float*)d_in[8];
    const float* W_attn   = (const float*)d_in[9];
    const float* W_fc     = (const float*)d_in[10];
    const float* b_fc     = (const float*)d_in[11];
    float* out = (float*)d_out;

    // workspace layout (floats)
    constexpr size_t SZ_KEYS = (size_t)NB * NS * NU;   // 507,904
    constexpr size_t SZ_WZ   = (size_t)2 * NU * NG;    // 524,288
    constexpr size_t SZ_ZEMB = (size_t)NB * NT * NG;   // 1,966,080
    constexpr size_t SZ_ACT  = (size_t)NB * NT * NU;   // 491,520
    float* keys     = (float*)d_ws;
    float* Wz       = keys + SZ_KEYS;
    float* z_emb    = Wz + SZ_WZ;
    float* h_all    = z_emb + SZ_ZEMB;
    float* ctx_all  = h_all + SZ_ACT;
    float* attn_all = ctx_all + SZ_ACT;

    keys_kernel<<<(NB * NS) / 8, 256, 0, stream>>>(memory, W_mem, keys);
    fuse_wz_kernel<<<dim3(NG / 256, (2 * NU) / 8), 256, 0, stream>>>(W_k, W_r,
                                                                     W_attn, Wz);
    zemb_kernel<<<dim3(NG / 256, (NB * NT) / 8), 256, 0, stream>>>(inputs, emb,
                                                                   W_k, b_lstm,
                                                                   z_emb);
    recurrence_kernel<<<NB, 1024, 0, stream>>>(z_emb, sample_h, sample_c, Wz,
                                               W_r, memory, keys, h_all, ctx_all);
    attn_kernel<<<(NB * NT) / 8, 256, 0, stream>>>(h_all, ctx_all, W_attn,
                                                   attn_all);
    out_gemm<<<dim3(NV / BN, (NB * NT) / BM), 256, 0, stream>>>(attn_all, W_fc,
                                                                b_fc, out);
}

// Round 3
// 1088.036 us; speedup vs baseline: 1.4993x; 1.1432x over previous
//
#include <hip/hip_runtime.h>
#include <hip/hip_bf16.h>
#include <math.h>

// Problem dims (compile-time)
constexpr int NB = 64;     // batch
constexpr int NT = 30;     // decode steps
constexpr int NS = 31;     // encoder positions
constexpr int NE = 128;    // embedding dim
constexpr int NU = 256;    // hidden
constexpr int NV = 32000;  // vocab
constexpr int NG = 4 * NU;    // 1024 (gates)

__device__ __forceinline__ float sigmoidf_(float x) {
    return 1.0f / (1.0f + __expf(-x));
}

// ---------------------------------------------------------------------------
// keys[b,s,v] = sum_u memory[b,s,u] * W_mem[u,v]
// ---------------------------------------------------------------------------
__global__ __launch_bounds__(256) void keys_kernel(
    const float* __restrict__ memory, const float* __restrict__ W_mem,
    float* __restrict__ keys) {
    const int row0 = blockIdx.x * 8;
    const int u = threadIdx.x;
    __shared__ float mS[8][NU];
#pragma unroll
    for (int r = 0; r < 8; ++r) mS[r][u] = memory[(row0 + r) * NU + u];
    __syncthreads();
    float acc[8] = {0, 0, 0, 0, 0, 0, 0, 0};
#pragma unroll 4
    for (int v = 0; v < NU; ++v) {
        float w = W_mem[v * NU + u];
#pragma unroll
        for (int r = 0; r < 8; ++r) acc[r] += mS[r][v] * w;
    }
#pragma unroll
    for (int r = 0; r < 8; ++r) keys[(row0 + r) * NU + u] = acc[r];
}

// ---------------------------------------------------------------------------
// Fused recurrent weights, written as 4 per-u-slice panels:
//   Wz[i][n] = W_attn[i][:] . W_k[128:384][n]  (+ W_r[i][n] if i<256)
// Panel layout: Wzp[qb][i][lc], qb = u-slice (u>>6), i = input row (0..511),
// lc = gate*64 + (u&63)  -> each recurrence block streams a contiguous
// 512x256 panel (1KB rows, fully coalesced, disjoint across blocks).
// ---------------------------------------------------------------------------
__global__ __launch_bounds__(256) void fuse_wz_kernel(
    const float* __restrict__ W_k,   // [384, NG]
    const float* __restrict__ W_r,   // [NU, NG]
    const float* __restrict__ W_a,   // [2*NU, NU]
    float* __restrict__ Wzp)         // [4][512][256]
{
    const int col = blockIdx.x * 256 + threadIdx.x;  // z-col n, 0..1023
    const int rb = blockIdx.y * 8;
    __shared__ float waS[8][NU];
#pragma unroll
    for (int r = 0; r < 8; ++r) waS[r][threadIdx.x] = W_a[(size_t)(rb + r) * NU + threadIdx.x];
    __syncthreads();
    float acc[8] = {};
#pragma unroll 4
    for (int j = 0; j < NU; ++j) {
        float w = W_k[(size_t)(NE + j) * NG + col];
#pragma unroll
        for (int r = 0; r < 8; ++r) acc[r] += waS[r][j] * w;
    }
    const int gate = col >> 8, u = col & 255;
    const int qb = u >> 6, lc = gate * 64 + (u & 63);
#pragma unroll
    for (int r = 0; r < 8; ++r) {
        int i = rb + r;
        float v = acc[r];
        if (i < NU) v += W_r[(size_t)i * NG + col];
        Wzp[(size_t)qb * 512 * 256 + (size_t)i * 256 + lc] = v;
    }
}

// ---------------------------------------------------------------------------
// z_emb[m][n] = emb[inputs[m]] @ W_k[0:128] + b_lstm,  m = b*NT + t
// ---------------------------------------------------------------------------
__global__ __launch_bounds__(256) void zemb_kernel(
    const int* __restrict__ inputs, const float* __restrict__ emb,
    const float* __restrict__ W_k, const float* __restrict__ b_lstm,
    float* __restrict__ z_emb)
{
    const int col = blockIdx.x * 256 + threadIdx.x;
    const int m0 = blockIdx.y * 8;
    __shared__ float eS[8][NE];
    for (int i = threadIdx.x; i < 8 * NE; i += 256) {
        int r = i >> 7, e = i & 127;
        eS[r][e] = emb[(size_t)inputs[m0 + r] * NE + e];
    }
    __syncthreads();
    float acc[8] = {};
#pragma unroll 4
    for (int e = 0; e < NE; ++e) {
        float w = W_k[(size_t)e * NG + col];
#pragma unroll
        for (int r = 0; r < 8; ++r) acc[r] += eS[r][e] * w;
    }
    float bb = b_lstm[col];
#pragma unroll
    for (int r = 0; r < 8; ++r) z_emb[(size_t)(m0 + r) * NG + col] = acc[r] + bb;
}

// ---------------------------------------------------------------------------
// Cooperative recurrence: 256 blocks x 1024 threads (full chip).
// Block bid: batch b = bid&63, u-slice qb = bid>>6 (u in [64qb, 64qb+64)).
// Per step: z-slice GEMV (16-way k-split over the 512x256 panel) -> gates for
// own 64 u's -> publish h-slice to h_all via agent-scope atomics -> one
// 4-block counter barrier -> read full h -> redundant scores/softmax/ctx.
// Cross-block data moves ONLY via agent-scope relaxed atomics (cross-XCD
// coherent, no L2-invalidating acquire fences); __syncthreads' vmcnt drain
// orders data stores before the flag add. Counters zeroed per launch.
// ---------------------------------------------------------------------------
__global__ __launch_bounds__(1024, 4) void recurrence_coop(
    const float* __restrict__ z_emb,     // [NB*NT, NG] (includes bias)
    const float* __restrict__ sample_h,
    const float* __restrict__ sample_c,
    const float* __restrict__ Wzp,       // [4][512][256] panels
    const float* __restrict__ W_r,       // [NU, NG] raw (t==0 path)
    const float* __restrict__ memory,    // [NB, NS, NU]
    const float* __restrict__ keys,      // [NB, NS, NU]
    float* __restrict__ h_all,           // [NB*NT, NU] (also exchange buf)
    float* __restrict__ ctx_all,         // [NB*NT, NU]
    unsigned* __restrict__ bar)          // [NB] counters, pre-zeroed
{
    const int bid = blockIdx.x;
    const int b  = bid & 63;
    const int qb = bid >> 6;
    const int tid = threadIdx.x;

    __shared__ float memS[NS * NU];    // 31 KB: memory[b] (ctx phase)
    __shared__ float zPart[16 * 256];  // 16 KB: z partials
    __shared__ float actS[2 * NU];     // [h | ctx]
    __shared__ float scS[32];

    const float* memb = memory + (size_t)b * NS * NU;
    const float* keyb = keys + (size_t)b * NS * NU;
    for (int i = tid; i < NS * NU / 4; i += 1024)
        ((float4*)memS)[i] = ((const float4*)memb)[i];
    if (tid < NU) actS[tid] = sample_h[b * NU + tid];
    float c_reg = (tid < 64) ? sample_c[b * NU + qb * 64 + tid] : 0.0f;

    const int colq = tid & 63;   // local col-quad (4 cols at lc = colq*4)
    const int p    = tid >> 6;   // k-partition 0..15 (wave-uniform)
    const int gate = colq >> 4, wq = colq & 15;
    const int ncol = gate * 256 + qb * 64 + wq * 4;  // global z-col base
    const float* panel = Wzp + (size_t)qb * 512 * 256;
    const float* zerow = z_emb + (size_t)(b * NT) * NG + ncol;
    unsigned* ctr = bar + b;

    __syncthreads();

    for (int t = 0; t < NT; ++t) {
        // --- P2: z-slice partials ---
        {
            float4 acc = (p == 0) ? *(const float4*)(zerow + (size_t)t * NG)
                                  : make_float4(0.f, 0.f, 0.f, 0.f);
            if (t == 0) {
                // attn_0 = 0: z = z_emb + h0 @ W_r (k-range 16 of 256)
                const float* ap = actS + p * 16;
#pragma unroll
                for (int k = 0; k < 16; ++k) {
                    float a = ap[k];
                    float4 w = *(const float4*)(W_r + (size_t)(p * 16 + k) * NG + ncol);
                    acc.x += a * w.x; acc.y += a * w.y;
                    acc.z += a * w.z; acc.w += a * w.w;
                }
            } else {
                // z = z_emb + [h|ctx] @ Wz (k-range 32 of 512, panel rows 1KB)
                const float* ap = actS + p * 32;
                const float* wp = panel + (size_t)(p * 32) * 256 + colq * 4;
#pragma unroll 8
                for (int k = 0; k < 32; ++k) {
                    float a = ap[k];
                    float4 w = *(const float4*)(wp + k * 256);
                    acc.x += a * w.x; acc.y += a * w.y;
                    acc.z += a * w.z; acc.w += a * w.w;
                }
            }
            *(float4*)(zPart + p * 256 + colq * 4) = acc;
        }
        __syncthreads();

        // --- P3: reduce 16 partials + LSTM gates for own u-slice ---
        const size_t m = (size_t)b * NT + t;
        if (tid < 64) {
            float zv[4];
#pragma unroll
            for (int g = 0; g < 4; ++g) {
                float s = 0.f;
#pragma unroll
                for (int q = 0; q < 16; ++q) s += zPart[q * 256 + g * 64 + tid];
                zv[g] = s;
            }
            // gates order: i, f, g, o
            c_reg = sigmoidf_(zv[1]) * c_reg + sigmoidf_(zv[0]) * tanhf(zv[2]);
            float h = sigmoidf_(zv[3]) * tanhf(c_reg);
            __hip_atomic_store(h_all + m * NU + qb * 64 + tid, h,
                               __ATOMIC_RELAXED, __HIP_MEMORY_SCOPE_AGENT);
        }
        __syncthreads();   // drains vmcnt: h-slice stores complete before flag

        // --- 4-block barrier (monotonic counter, target 4*(t+1)) ---
        if (tid == 0) {
            __hip_atomic_fetch_add(ctr, 1u, __ATOMIC_RELAXED,
                                   __HIP_MEMORY_SCOPE_AGENT);
            const unsigned tgt = 4u * (unsigned)(t + 1);
            while (__hip_atomic_load(ctr, __ATOMIC_RELAXED,
                                     __HIP_MEMORY_SCOPE_AGENT) < tgt)
                __builtin_amdgcn_s_sleep(2);
        }
        __syncthreads();

        // --- read full h (coherent loads) ---
        if (tid < NU)
            actS[tid] = __hip_atomic_load(h_all + m * NU + tid,
                                          __ATOMIC_RELAXED,
                                          __HIP_MEMORY_SCOPE_AGENT);
        __syncthreads();

        // --- P4: scores (redundant per block); keys from L2 ---
        {
            const int s = tid >> 5, j = tid & 31;
            if (s < NS) {
                float sp = 0.0f;
#pragma unroll
                for (int i = 0; i < 8; ++i)
                    sp += actS[i * 32 + j] * keyb[s * NU + i * 32 + j];
#pragma unroll
                for (int msk = 16; msk; msk >>= 1) sp += __shfl_xor(sp, msk, 32);
                if (j == 0) scS[s] = sp;
            }
        }
        __syncthreads();

        // --- P5: softmax + full ctx (redundant -> no second barrier) ---
        if (tid < NU) {
            float mx = scS[0];
#pragma unroll
            for (int s = 1; s < NS; ++s) mx = fmaxf(mx, scS[s]);
            float sumE = 0.0f, ctx = 0.0f;
#pragma unroll 4
            for (int s = 0; s < NS; ++s) {
                float e = __expf(scS[s] - mx);
                sumE += e;
                ctx += e * memS[s * NU + tid];
            }
            ctx /= sumE;
            actS[NU + tid] = ctx;
            if (qb == 0) ctx_all[m * NU + tid] = ctx;
        }
        __syncthreads();
    }
}

// ---------------------------------------------------------------------------
// attn_all[m] = concat(h_all[m], ctx_all[m]) @ W_attn
// ---------------------------------------------------------------------------
__global__ __launch_bounds__(256) void attn_kernel(
    const float* __restrict__ h_all, const float* __restrict__ ctx_all,
    const float* __restrict__ W_a, float* __restrict__ attn_all)
{
    const int j = threadIdx.x;
    const int m0 = blockIdx.x * 8;
    __shared__ float hS[8][NU], cS[8][NU];
    for (int i = j; i < 8 * NU; i += 256) {
        int r = i >> 8, k = i & 255;
        hS[r][k] = h_all[(size_t)(m0 + r) * NU + k];
        cS[r][k] = ctx_all[(size_t)(m0 + r) * NU + k];
    }
    __syncthreads();
    float acc[8] = {};
#pragma unroll 2
    for (int k = 0; k < NU; ++k) {
        float w1 = W_a[(size_t)k * NU + j];
        float w2 = W_a[(size_t)(NU + k) * NU + j];
#pragma unroll
        for (int r = 0; r < 8; ++r) acc[r] += hS[r][k] * w1 + cS[r][k] * w2;
    }
#pragma unroll
    for (int r = 0; r < 8; ++r) attn_all[(size_t)(m0 + r) * NU + j] = acc[r];
}

// ---------------------------------------------------------------------------
// out[m, n] = attn_all[m, :] @ W_fc[:, n] + b_fc[n]
// Register double-buffered staging (issue-early / write-late).
// ---------------------------------------------------------------------------
constexpr int BM = 128, BN = 128, KC = 32, KTOT = NU;

__global__ __launch_bounds__(256) void out_gemm(
    const float* __restrict__ A,
    const float* __restrict__ Wfc,
    const float* __restrict__ bfc,
    float* __restrict__ out)
{
    const int n0 = blockIdx.x * BN;
    const int m0 = blockIdx.y * BM;
    const int tid = threadIdx.x;
    const int tx = tid & 15, ty = tid >> 4;

    __shared__ float As[KC][BM + 4];
    __shared__ float Bs[KC][BN];

    float acc[2][4][2][4] = {};

    const int kq = tid & 7,  r0 = tid >> 3;
    const int nq = tid & 31, kr0 = tid >> 5;

    float4 aR[4], bR[4];

#pragma unroll
    for (int p = 0; p < 4; ++p)
        aR[p] = *(const float4*)(A + (size_t)(m0 + r0 + p * 32) * KTOT + kq * 4);
#pragma unroll
    for (int p = 0; p < 4; ++p)
        bR[p] = *(const float4*)(Wfc + (size_t)(kr0 + p * 8) * NV + n0 + nq * 4);
#pragma unroll
    for (int p = 0; p < 4; ++p) {
        int r = r0 + p * 32;
        As[kq * 4 + 0][r] = aR[p].x;
        As[kq * 4 + 1][r] = aR[p].y;
        As[kq * 4 + 2][r] = aR[p].z;
        As[kq * 4 + 3][r] = aR[p].w;
        *(float4*)&Bs[kr0 + p * 8][nq * 4] = bR[p];
    }
    __syncthreads();

    for (int kb = 0; kb < KTOT; kb += KC) {
        const bool more = (kb + KC) < KTOT;
        if (more) {
#pragma unroll
            for (int p = 0; p < 4; ++p)
                aR[p] = *(const float4*)(A + (size_t)(m0 + r0 + p * 32) * KTOT + kb + KC + kq * 4);
#pragma unroll
            for (int p = 0; p < 4; ++p)
                bR[p] = *(const float4*)(Wfc + (size_t)(kb + KC + kr0 + p * 8) * NV + n0 + nq * 4);
        }

#pragma unroll 4
        for (int k = 0; k < KC; ++k) {
            float4 a0 = *(const float4*)&As[k][ty * 4];
            float4 a1 = *(const float4*)&As[k][64 + ty * 4];
            float4 b0 = *(const float4*)&Bs[k][tx * 4];
            float4 b1 = *(const float4*)&Bs[k][64 + tx * 4];
            float am[2][4] = {{a0.x, a0.y, a0.z, a0.w}, {a1.x, a1.y, a1.z, a1.w}};
            float bv[2][4] = {{b0.x, b0.y, b0.z, b0.w}, {b1.x, b1.y, b1.z, b1.w}};
#pragma unroll
            for (int im = 0; im < 2; ++im)
#pragma unroll
                for (int i = 0; i < 4; ++i)
#pragma unroll
                    for (int jn = 0; jn < 2; ++jn)
#pragma unroll
                        for (int j = 0; j < 4; ++j)
                            acc[im][i][jn][j] += am[im][i] * bv[jn][j];
        }
        __syncthreads();

        if (more) {
#pragma unroll
            for (int p = 0; p < 4; ++p) {
                int r = r0 + p * 32;
                As[kq * 4 + 0][r] = aR[p].x;
                As[kq * 4 + 1][r] = aR[p].y;
                As[kq * 4 + 2][r] = aR[p].z;
                As[kq * 4 + 3][r] = aR[p].w;
                *(float4*)&Bs[kr0 + p * 8][nq * 4] = bR[p];
            }
            __syncthreads();
        }
    }

    float4 bias[2];
    bias[0] = *(const float4*)(bfc + n0 + tx * 4);
    bias[1] = *(const float4*)(bfc + n0 + 64 + tx * 4);
#pragma unroll
    for (int im = 0; im < 2; ++im)
#pragma unroll
        for (int i = 0; i < 4; ++i) {
            int m = m0 + im * 64 + ty * 4 + i;
#pragma unroll
            for (int jn = 0; jn < 2; ++jn) {
                float4 v;
                float4 bb = bias[jn];
                v.x = acc[im][i][jn][0] + bb.x;
                v.y = acc[im][i][jn][1] + bb.y;
                v.z = acc[im][i][jn][2] + bb.z;
                v.w = acc[im][i][jn][3] + bb.w;
                *(float4*)(out + (size_t)m * NV + n0 + jn * 64 + tx * 4) = v;
            }
        }
}

// ---------------------------------------------------------------------------
extern "C" void kernel_launch(void* const* d_in, const int* in_sizes, int n_in,
                              void* d_out, int out_size, void* d_ws, size_t ws_size,
                              hipStream_t stream) {
    const int*   inputs   = (const int*)  d_in[0];
    const float* memory   = (const float*)d_in[1];
    const float* sample_h = (const float*)d_in[2];
    const float* sample_c = (const float*)d_in[3];
    const float* emb      = (const float*)d_in[4];
    const float* W_k      = (const float*)d_in[5];
    const float* W_r      = (const float*)d_in[6];
    const float* b_lstm   = (const float*)d_in[7];
    const float* W_mem    = (const float*)d_in[8];
    const float* W_attn   = (const float*)d_in[9];
    const float* W_fc     = (const float*)d_in[10];
    const float* b_fc     = (const float*)d_in[11];
    float* out = (float*)d_out;

    // workspace layout (floats)
    constexpr size_t SZ_KEYS = (size_t)NB * NS * NU;   // 507,904
    constexpr size_t SZ_WZ   = (size_t)4 * 512 * 256;  // 524,288
    constexpr size_t SZ_ZEMB = (size_t)NB * NT * NG;   // 1,966,080
    constexpr size_t SZ_ACT  = (size_t)NB * NT * NU;   // 491,520
    float* keys     = (float*)d_ws;
    float* Wzp      = keys + SZ_KEYS;
    float* z_emb    = Wzp + SZ_WZ;
    float* h_all    = z_emb + SZ_ZEMB;
    float* ctx_all  = h_all + SZ_ACT;
    float* attn_all = ctx_all + SZ_ACT;
    unsigned* bar   = (unsigned*)(attn_all + SZ_ACT);  // [NB]

    keys_kernel<<<(NB * NS) / 8, 256, 0, stream>>>(memory, W_mem, keys);
    fuse_wz_kernel<<<dim3(NG / 256, (2 * NU) / 8), 256, 0, stream>>>(W_k, W_r,
                                                                     W_attn, Wzp);
    zemb_kernel<<<dim3(NG / 256, (NB * NT) / 8), 256, 0, stream>>>(inputs, emb,
                                                                   W_k, b_lstm,
                                                                   z_emb);
    hipMemsetAsync(bar, 0, NB * sizeof(unsigned), stream);

    {
        void* kargs[] = {
            (void*)&z_emb, (void*)&sample_h, (void*)&sample_c, (void*)&Wzp,
            (void*)&W_r, (void*)&memory, (void*)&keys, (void*)&h_all,
            (void*)&ctx_all, (void*)&bar
        };
        hipLaunchCooperativeKernel((const void*)recurrence_coop,
                                   dim3(NB * 4), dim3(1024), kargs, 0, stream);
    }

    attn_kernel<<<(NB * NT) / 8, 256, 0, stream>>>(h_all, ctx_all, W_attn,
                                                   attn_all);
    out_gemm<<<dim3(NV / BN, (NB * NT) / BM), 256, 0, stream>>>(attn_all, W_fc,
                                                                b_fc, out);
}

// Round 4
// 940.391 us; speedup vs baseline: 1.7347x; 1.1570x over previous
//
#include <hip/hip_runtime.h>
#include <hip/hip_bf16.h>
#include <math.h>

// Problem dims (compile-time)
constexpr int NB = 64;     // batch
constexpr int NT = 30;     // decode steps
constexpr int NS = 31;     // encoder positions
constexpr int NE = 128;    // embedding dim
constexpr int NU = 256;    // hidden
constexpr int NV = 32000;  // vocab
constexpr int NG = 4 * NU;    // 1024 (gates)

typedef unsigned short u16;
typedef __attribute__((ext_vector_type(8))) short bf16x8;
typedef __attribute__((ext_vector_type(4))) float f32x4;

__device__ __forceinline__ float sigmoidf_(float x) {
    return 1.0f / (1.0f + __expf(-x));
}

__device__ __forceinline__ u16 rne_bf16(float x) {
    unsigned u = __float_as_uint(x);
    unsigned r = u + 0x7fffu + ((u >> 16) & 1u);
    return (u16)(r >> 16);
}

// ---------------------------------------------------------------------------
// keys[b,s,v] = sum_u memory[b,s,u] * W_mem[u,v]
// ---------------------------------------------------------------------------
__global__ __launch_bounds__(256) void keys_kernel(
    const float* __restrict__ memory, const float* __restrict__ W_mem,
    float* __restrict__ keys) {
    const int row0 = blockIdx.x * 8;
    const int u = threadIdx.x;
    __shared__ float mS[8][NU];
#pragma unroll
    for (int r = 0; r < 8; ++r) mS[r][u] = memory[(row0 + r) * NU + u];
    __syncthreads();
    float acc[8] = {0, 0, 0, 0, 0, 0, 0, 0};
#pragma unroll 4
    for (int v = 0; v < NU; ++v) {
        float w = W_mem[v * NU + u];
#pragma unroll
        for (int r = 0; r < 8; ++r) acc[r] += mS[r][v] * w;
    }
#pragma unroll
    for (int r = 0; r < 8; ++r) keys[(row0 + r) * NU + u] = acc[r];
}

// ---------------------------------------------------------------------------
// Fused recurrent weights, written as 4 per-u-slice panels:
//   Wz[i][n] = W_attn[i][:] . W_k[128:384][n]  (+ W_r[i][n] if i<256)
// Panel layout: Wzp[qb][i][lc], lc = gate*64 + (u&63).
// ---------------------------------------------------------------------------
__global__ __launch_bounds__(256) void fuse_wz_kernel(
    const float* __restrict__ W_k,   // [384, NG]
    const float* __restrict__ W_r,   // [NU, NG]
    const float* __restrict__ W_a,   // [2*NU, NU]
    float* __restrict__ Wzp)         // [4][512][256]
{
    const int col = blockIdx.x * 256 + threadIdx.x;  // z-col n, 0..1023
    const int rb = blockIdx.y * 8;
    __shared__ float waS[8][NU];
#pragma unroll
    for (int r = 0; r < 8; ++r) waS[r][threadIdx.x] = W_a[(size_t)(rb + r) * NU + threadIdx.x];
    __syncthreads();
    float acc[8] = {};
#pragma unroll 4
    for (int j = 0; j < NU; ++j) {
        float w = W_k[(size_t)(NE + j) * NG + col];
#pragma unroll
        for (int r = 0; r < 8; ++r) acc[r] += waS[r][j] * w;
    }
    const int gate = col >> 8, u = col & 255;
    const int qb = u >> 6, lc = gate * 64 + (u & 63);
#pragma unroll
    for (int r = 0; r < 8; ++r) {
        int i = rb + r;
        float v = acc[r];
        if (i < NU) v += W_r[(size_t)i * NG + col];
        Wzp[(size_t)qb * 512 * 256 + (size_t)i * 256 + lc] = v;
    }
}

// ---------------------------------------------------------------------------
// z_emb[m][n] = emb[inputs[m]] @ W_k[0:128] + b_lstm,  m = b*NT + t
// ---------------------------------------------------------------------------
__global__ __launch_bounds__(256) void zemb_kernel(
    const int* __restrict__ inputs, const float* __restrict__ emb,
    const float* __restrict__ W_k, const float* __restrict__ b_lstm,
    float* __restrict__ z_emb)
{
    const int col = blockIdx.x * 256 + threadIdx.x;
    const int m0 = blockIdx.y * 8;
    __shared__ float eS[8][NE];
    for (int i = threadIdx.x; i < 8 * NE; i += 256) {
        int r = i >> 7, e = i & 127;
        eS[r][e] = emb[(size_t)inputs[m0 + r] * NE + e];
    }
    __syncthreads();
    float acc[8] = {};
#pragma unroll 4
    for (int e = 0; e < NE; ++e) {
        float w = W_k[(size_t)e * NG + col];
#pragma unroll
        for (int r = 0; r < 8; ++r) acc[r] += eS[r][e] * w;
    }
    float bb = b_lstm[col];
#pragma unroll
    for (int r = 0; r < 8; ++r) z_emb[(size_t)(m0 + r) * NG + col] = acc[r] + bb;
}

// ---------------------------------------------------------------------------
// Cooperative recurrence: 256 blocks x 1024 threads (full chip). Unchanged
// from R3 (verified): b = bid&63, u-slice qb = bid>>6; agent-scope exchange.
// ---------------------------------------------------------------------------
__global__ __launch_bounds__(1024, 4) void recurrence_coop(
    const float* __restrict__ z_emb,     // [NB*NT, NG] (includes bias)
    const float* __restrict__ sample_h,
    const float* __restrict__ sample_c,
    const float* __restrict__ Wzp,       // [4][512][256] panels
    const float* __restrict__ W_r,       // [NU, NG] raw (t==0 path)
    const float* __restrict__ memory,    // [NB, NS, NU]
    const float* __restrict__ keys,      // [NB, NS, NU]
    float* __restrict__ h_all,           // [NB*NT, NU] (also exchange buf)
    float* __restrict__ ctx_all,         // [NB*NT, NU]
    unsigned* __restrict__ bar)          // [NB] counters, pre-zeroed
{
    const int bid = blockIdx.x;
    const int b  = bid & 63;
    const int qb = bid >> 6;
    const int tid = threadIdx.x;

    __shared__ float memS[NS * NU];    // 31 KB
    __shared__ float zPart[16 * 256];  // 16 KB
    __shared__ float actS[2 * NU];     // [h | ctx]
    __shared__ float scS[32];

    const float* memb = memory + (size_t)b * NS * NU;
    const float* keyb = keys + (size_t)b * NS * NU;
    for (int i = tid; i < NS * NU / 4; i += 1024)
        ((float4*)memS)[i] = ((const float4*)memb)[i];
    if (tid < NU) actS[tid] = sample_h[b * NU + tid];
    float c_reg = (tid < 64) ? sample_c[b * NU + qb * 64 + tid] : 0.0f;

    const int colq = tid & 63;
    const int p    = tid >> 6;
    const int gate = colq >> 4, wq = colq & 15;
    const int ncol = gate * 256 + qb * 64 + wq * 4;
    const float* panel = Wzp + (size_t)qb * 512 * 256;
    const float* zerow = z_emb + (size_t)(b * NT) * NG + ncol;
    unsigned* ctr = bar + b;

    __syncthreads();

    for (int t = 0; t < NT; ++t) {
        // --- P2: z-slice partials ---
        {
            float4 acc = (p == 0) ? *(const float4*)(zerow + (size_t)t * NG)
                                  : make_float4(0.f, 0.f, 0.f, 0.f);
            if (t == 0) {
                const float* ap = actS + p * 16;
#pragma unroll
                for (int k = 0; k < 16; ++k) {
                    float a = ap[k];
                    float4 w = *(const float4*)(W_r + (size_t)(p * 16 + k) * NG + ncol);
                    acc.x += a * w.x; acc.y += a * w.y;
                    acc.z += a * w.z; acc.w += a * w.w;
                }
            } else {
                const float* ap = actS + p * 32;
                const float* wp = panel + (size_t)(p * 32) * 256 + colq * 4;
#pragma unroll 8
                for (int k = 0; k < 32; ++k) {
                    float a = ap[k];
                    float4 w = *(const float4*)(wp + k * 256);
                    acc.x += a * w.x; acc.y += a * w.y;
                    acc.z += a * w.z; acc.w += a * w.w;
                }
            }
            *(float4*)(zPart + p * 256 + colq * 4) = acc;
        }
        __syncthreads();

        // --- P3: reduce + gates ---
        const size_t m = (size_t)b * NT + t;
        if (tid < 64) {
            float zv[4];
#pragma unroll
            for (int g = 0; g < 4; ++g) {
                float s = 0.f;
#pragma unroll
                for (int q = 0; q < 16; ++q) s += zPart[q * 256 + g * 64 + tid];
                zv[g] = s;
            }
            c_reg = sigmoidf_(zv[1]) * c_reg + sigmoidf_(zv[0]) * tanhf(zv[2]);
            float h = sigmoidf_(zv[3]) * tanhf(c_reg);
            __hip_atomic_store(h_all + m * NU + qb * 64 + tid, h,
                               __ATOMIC_RELAXED, __HIP_MEMORY_SCOPE_AGENT);
        }
        __syncthreads();

        // --- 4-block barrier ---
        if (tid == 0) {
            __hip_atomic_fetch_add(ctr, 1u, __ATOMIC_RELAXED,
                                   __HIP_MEMORY_SCOPE_AGENT);
            const unsigned tgt = 4u * (unsigned)(t + 1);
            while (__hip_atomic_load(ctr, __ATOMIC_RELAXED,
                                     __HIP_MEMORY_SCOPE_AGENT) < tgt)
                __builtin_amdgcn_s_sleep(2);
        }
        __syncthreads();

        if (tid < NU)
            actS[tid] = __hip_atomic_load(h_all + m * NU + tid,
                                          __ATOMIC_RELAXED,
                                          __HIP_MEMORY_SCOPE_AGENT);
        __syncthreads();

        // --- P4: scores ---
        {
            const int s = tid >> 5, j = tid & 31;
            if (s < NS) {
                float sp = 0.0f;
#pragma unroll
                for (int i = 0; i < 8; ++i)
                    sp += actS[i * 32 + j] * keyb[s * NU + i * 32 + j];
#pragma unroll
                for (int msk = 16; msk; msk >>= 1) sp += __shfl_xor(sp, msk, 32);
                if (j == 0) scS[s] = sp;
            }
        }
        __syncthreads();

        // --- P5: softmax + ctx ---
        if (tid < NU) {
            float mx = scS[0];
#pragma unroll
            for (int s = 1; s < NS; ++s) mx = fmaxf(mx, scS[s]);
            float sumE = 0.0f, ctx = 0.0f;
#pragma unroll 4
            for (int s = 0; s < NS; ++s) {
                float e = __expf(scS[s] - mx);
                sumE += e;
                ctx += e * memS[s * NU + tid];
            }
            ctx /= sumE;
            actS[NU + tid] = ctx;
            if (qb == 0) ctx_all[m * NU + tid] = ctx;
        }
        __syncthreads();
    }
}

// ---------------------------------------------------------------------------
// attn_all[m] = concat(h_all[m], ctx_all[m]) @ W_attn
// Also emits the bf16 split Ah/Al for the MFMA output GEMM.
// ---------------------------------------------------------------------------
__global__ __launch_bounds__(256) void attn_kernel(
    const float* __restrict__ h_all, const float* __restrict__ ctx_all,
    const float* __restrict__ W_a, float* __restrict__ attn_all,
    u16* __restrict__ Ahl)   // [2][NB*NT][NU]
{
    const int j = threadIdx.x;
    const int m0 = blockIdx.x * 8;
    __shared__ float hS[8][NU], cS[8][NU];
    for (int i = j; i < 8 * NU; i += 256) {
        int r = i >> 8, k = i & 255;
        hS[r][k] = h_all[(size_t)(m0 + r) * NU + k];
        cS[r][k] = ctx_all[(size_t)(m0 + r) * NU + k];
    }
    __syncthreads();
    float acc[8] = {};
#pragma unroll 2
    for (int k = 0; k < NU; ++k) {
        float w1 = W_a[(size_t)k * NU + j];
        float w2 = W_a[(size_t)(NU + k) * NU + j];
#pragma unroll
        for (int r = 0; r < 8; ++r) acc[r] += hS[r][k] * w1 + cS[r][k] * w2;
    }
#pragma unroll
    for (int r = 0; r < 8; ++r) {
        float a = acc[r];
        size_t m = (size_t)(m0 + r) * NU + j;
        attn_all[m] = a;
        u16 h = rne_bf16(a);
        float hf = __uint_as_float((unsigned)h << 16);
        Ahl[m] = h;
        Ahl[(size_t)NB * NT * NU + m] = rne_bf16(a - hf);
    }
}

// ---------------------------------------------------------------------------
// Pack W_fc [256][32000] f32 -> Bt [32000][512] bf16:  row n = [h(256)|l(256)]
// n-major so MFMA B-fragments are contiguous 16B/lane loads.
// ---------------------------------------------------------------------------
__global__ __launch_bounds__(256) void wfc_pack(
    const float* __restrict__ Wfc, u16* __restrict__ Bt)
{
    const int n0 = blockIdx.x * 64;
    const int tid = threadIdx.x;
    __shared__ __align__(16) u16 tS[64][264];

#pragma unroll
    for (int part = 0; part < 2; ++part) {
        for (int kk = 0; kk < 256; kk += 4) {
            int k = kk + (tid >> 6);
            int n = tid & 63;
            float v = Wfc[(size_t)k * NV + n0 + n];
            u16 h = rne_bf16(v);
            u16 w = h;
            if (part) {
                float hf = __uint_as_float((unsigned)h << 16);
                w = rne_bf16(v - hf);
            }
            tS[n][k] = w;
        }
        __syncthreads();
        {
            int n = tid >> 2;
#pragma unroll
            for (int i = 0; i < 8; ++i) {
                int c = (tid & 3) + i * 4;   // 16B chunk index 0..31
                *(uint4*)(Bt + (size_t)(n0 + n) * 512 + part * 256 + c * 8) =
                    *(const uint4*)(&tS[n][c * 8]);
            }
        }
        __syncthreads();
    }
}

// ---------------------------------------------------------------------------
// MFMA output GEMM: out = A @ W_fc + b, via split-bf16 3-term product:
//   out ~= Ah@Bh + Al@Bh + Ah@Bl      (dropped Al@Bl ~ 2^-16 relative)
// 128x128 tile, 4 waves (2x2) of 64x64, fragments straight from L2 (no LDS,
// no barriers). k-mapping k=(lane>>4)*8+j used identically for A and B
// (any consistent permutation cancels); row/col = lane&15; C/D per m89.
// Bijective XCD swizzle: each XCD owns a contiguous n-chunk -> Bt panel +
// whole A stay L2-resident per XCD.
// ---------------------------------------------------------------------------
__global__ __launch_bounds__(256) void out_gemm_mfma(
    const u16* __restrict__ Ahl,    // [2][1920][256]
    const u16* __restrict__ Bt,     // [32000][512]
    const float* __restrict__ bfc,
    float* __restrict__ out)
{
    constexpr int NWG = (NV / 128) * ((NB * NT) / 128);  // 3750
    constexpr int qq = NWG / 8, rr = NWG % 8;            // 468, 6
    int bid = blockIdx.x;
    int xcd = bid & 7, idx = bid >> 3;
    int wg = (xcd < rr ? xcd * (qq + 1) : rr * (qq + 1) + (xcd - rr) * qq) + idx;
    const int nt = wg / 15, mt = wg % 15;   // m fastest within an XCD chunk
    const int n0 = nt * 128, m0 = mt * 128;

    const int tid = threadIdx.x;
    const int wave = tid >> 6, lane = tid & 63;
    const int wm = wave >> 1, wn = wave & 1;
    const int l15 = lane & 15, lq = lane >> 4;

    constexpr size_t ALOFF = (size_t)NB * NT * NU;  // Ah -> Al offset

    const u16* arow[4];
    const u16* brow[4];
#pragma unroll
    for (int f = 0; f < 4; ++f) {
        arow[f] = Ahl + (size_t)(m0 + wm * 64 + f * 16 + l15) * 256 + lq * 8;
        brow[f] = Bt + (size_t)(n0 + wn * 64 + f * 16 + l15) * 512 + lq * 8;
    }

    f32x4 acc[4][4] = {};

#pragma unroll
    for (int kk = 0; kk < 8; ++kk) {
        bf16x8 ah[4], al[4], bh[4], bl[4];
#pragma unroll
        for (int f = 0; f < 4; ++f) {
            ah[f] = *(const bf16x8*)(arow[f] + kk * 32);
            al[f] = *(const bf16x8*)(arow[f] + ALOFF + kk * 32);
            bh[f] = *(const bf16x8*)(brow[f] + kk * 32);
            bl[f] = *(const bf16x8*)(brow[f] + 256 + kk * 32);
        }
#pragma unroll
        for (int i = 0; i < 4; ++i)
#pragma unroll
            for (int j = 0; j < 4; ++j) {
                acc[i][j] = __builtin_amdgcn_mfma_f32_16x16x32_bf16(
                    ah[i], bh[j], acc[i][j], 0, 0, 0);
                acc[i][j] = __builtin_amdgcn_mfma_f32_16x16x32_bf16(
                    al[i], bh[j], acc[i][j], 0, 0, 0);
                acc[i][j] = __builtin_amdgcn_mfma_f32_16x16x32_bf16(
                    ah[i], bl[j], acc[i][j], 0, 0, 0);
            }
    }

    float bias[4];
#pragma unroll
    for (int j = 0; j < 4; ++j) bias[j] = bfc[n0 + wn * 64 + j * 16 + l15];
#pragma unroll
    for (int i = 0; i < 4; ++i) {
        const int mrow = m0 + wm * 64 + i * 16 + lq * 4;
#pragma unroll
        for (int j = 0; j < 4; ++j) {
            const size_t base = (size_t)mrow * NV + n0 + wn * 64 + j * 16 + l15;
#pragma unroll
            for (int rg = 0; rg < 4; ++rg)
                out[base + (size_t)rg * NV] = acc[i][j][rg] + bias[j];
        }
    }
}

// ---------------------------------------------------------------------------
// Fallback fp32 out_gemm (used only if workspace too small for Bt).
// ---------------------------------------------------------------------------
constexpr int BM = 128, BN = 128, KC = 32, KTOT = NU;

__global__ __launch_bounds__(256) void out_gemm(
    const float* __restrict__ A,
    const float* __restrict__ Wfc,
    const float* __restrict__ bfc,
    float* __restrict__ out)
{
    const int n0 = blockIdx.x * BN;
    const int m0 = blockIdx.y * BM;
    const int tid = threadIdx.x;
    const int tx = tid & 15, ty = tid >> 4;

    __shared__ float As[KC][BM + 4];
    __shared__ float Bs[KC][BN];

    float acc[2][4][2][4] = {};

    const int kq = tid & 7,  r0 = tid >> 3;
    const int nq = tid & 31, kr0 = tid >> 5;

    float4 aR[4], bR[4];

#pragma unroll
    for (int p = 0; p < 4; ++p)
        aR[p] = *(const float4*)(A + (size_t)(m0 + r0 + p * 32) * KTOT + kq * 4);
#pragma unroll
    for (int p = 0; p < 4; ++p)
        bR[p] = *(const float4*)(Wfc + (size_t)(kr0 + p * 8) * NV + n0 + nq * 4);
#pragma unroll
    for (int p = 0; p < 4; ++p) {
        int r = r0 + p * 32;
        As[kq * 4 + 0][r] = aR[p].x;
        As[kq * 4 + 1][r] = aR[p].y;
        As[kq * 4 + 2][r] = aR[p].z;
        As[kq * 4 + 3][r] = aR[p].w;
        *(float4*)&Bs[kr0 + p * 8][nq * 4] = bR[p];
    }
    __syncthreads();

    for (int kb = 0; kb < KTOT; kb += KC) {
        const bool more = (kb + KC) < KTOT;
        if (more) {
#pragma unroll
            for (int p = 0; p < 4; ++p)
                aR[p] = *(const float4*)(A + (size_t)(m0 + r0 + p * 32) * KTOT + kb + KC + kq * 4);
#pragma unroll
            for (int p = 0; p < 4; ++p)
                bR[p] = *(const float4*)(Wfc + (size_t)(kb + KC + kr0 + p * 8) * NV + n0 + nq * 4);
        }

#pragma unroll 4
        for (int k = 0; k < KC; ++k) {
            float4 a0 = *(const float4*)&As[k][ty * 4];
            float4 a1 = *(const float4*)&As[k][64 + ty * 4];
            float4 b0 = *(const float4*)&Bs[k][tx * 4];
            float4 b1 = *(const float4*)&Bs[k][64 + tx * 4];
            float am[2][4] = {{a0.x, a0.y, a0.z, a0.w}, {a1.x, a1.y, a1.z, a1.w}};
            float bv[2][4] = {{b0.x, b0.y, b0.z, b0.w}, {b1.x, b1.y, b1.z, b1.w}};
#pragma unroll
            for (int im = 0; im < 2; ++im)
#pragma unroll
                for (int i = 0; i < 4; ++i)
#pragma unroll
                    for (int jn = 0; jn < 2; ++jn)
#pragma unroll
                        for (int j = 0; j < 4; ++j)
                            acc[im][i][jn][j] += am[im][i] * bv[jn][j];
        }
        __syncthreads();

        if (more) {
#pragma unroll
            for (int p = 0; p < 4; ++p) {
                int r = r0 + p * 32;
                As[kq * 4 + 0][r] = aR[p].x;
                As[kq * 4 + 1][r] = aR[p].y;
                As[kq * 4 + 2][r] = aR[p].z;
                As[kq * 4 + 3][r] = aR[p].w;
                *(float4*)&Bs[kr0 + p * 8][nq * 4] = bR[p];
            }
            __syncthreads();
        }
    }

    float4 bias[2];
    bias[0] = *(const float4*)(bfc + n0 + tx * 4);
    bias[1] = *(const float4*)(bfc + n0 + 64 + tx * 4);
#pragma unroll
    for (int im = 0; im < 2; ++im)
#pragma unroll
        for (int i = 0; i < 4; ++i) {
            int m = m0 + im * 64 + ty * 4 + i;
#pragma unroll
            for (int jn = 0; jn < 2; ++jn) {
                float4 v;
                float4 bb = bias[jn];
                v.x = acc[im][i][jn][0] + bb.x;
                v.y = acc[im][i][jn][1] + bb.y;
                v.z = acc[im][i][jn][2] + bb.z;
                v.w = acc[im][i][jn][3] + bb.w;
                *(float4*)(out + (size_t)m * NV + n0 + jn * 64 + tx * 4) = v;
            }
        }
}

// ---------------------------------------------------------------------------
extern "C" void kernel_launch(void* const* d_in, const int* in_sizes, int n_in,
                              void* d_out, int out_size, void* d_ws, size_t ws_size,
                              hipStream_t stream) {
    const int*   inputs   = (const int*)  d_in[0];
    const float* memory   = (const float*)d_in[1];
    const float* sample_h = (const float*)d_in[2];
    const float* sample_c = (const float*)d_in[3];
    const float* emb      = (const float*)d_in[4];
    const float* W_k      = (const float*)d_in[5];
    const float* W_r      = (const float*)d_in[6];
    const float* b_lstm   = (const float*)d_in[7];
    const float* W_mem    = (const float*)d_in[8];
    const float* W_attn   = (const float*)d_in[9];
    const float* W_fc     = (const float*)d_in[10];
    const float* b_fc     = (const float*)d_in[11];
    float* out = (float*)d_out;

    // workspace layout (float units)
    constexpr size_t SZ_KEYS = (size_t)NB * NS * NU;        // 507,904
    constexpr size_t SZ_WZ   = (size_t)4 * 512 * 256;       // 524,288
    constexpr size_t SZ_ZEMB = (size_t)NB * NT * NG;        // 1,966,080
    constexpr size_t SZ_ACT  = (size_t)NB * NT * NU;        // 491,520
    constexpr size_t SZ_AHL  = SZ_ACT;                      // 2x bf16 = 1x f32
    constexpr size_t SZ_BAR  = 64;
    constexpr size_t SZ_BT   = (size_t)NV * 512 / 2;        // 8,192,000

    float* keys     = (float*)d_ws;
    float* Wzp      = keys + SZ_KEYS;
    float* z_emb    = Wzp + SZ_WZ;
    float* h_all    = z_emb + SZ_ZEMB;
    float* ctx_all  = h_all + SZ_ACT;
    float* attn_all = ctx_all + SZ_ACT;
    u16*   Ahl      = (u16*)(attn_all + SZ_ACT);
    unsigned* bar   = (unsigned*)(attn_all + SZ_ACT + SZ_AHL);
    float* bt_f     = attn_all + SZ_ACT + SZ_AHL + SZ_BAR;
    u16*   Bt       = (u16*)bt_f;

    const size_t need_bytes =
        (SZ_KEYS + SZ_WZ + SZ_ZEMB + 3 * SZ_ACT + SZ_AHL + SZ_BAR + SZ_BT) * 4;
    const bool use_mfma = ws_size >= need_bytes;

    keys_kernel<<<(NB * NS) / 8, 256, 0, stream>>>(memory, W_mem, keys);
    fuse_wz_kernel<<<dim3(NG / 256, (2 * NU) / 8), 256, 0, stream>>>(W_k, W_r,
                                                                     W_attn, Wzp);
    zemb_kernel<<<dim3(NG / 256, (NB * NT) / 8), 256, 0, stream>>>(inputs, emb,
                                                                   W_k, b_lstm,
                                                                   z_emb);
    if (use_mfma)
        wfc_pack<<<NV / 64, 256, 0, stream>>>(W_fc, Bt);

    hipMemsetAsync(bar, 0, NB * sizeof(unsigned), stream);

    {
        void* kargs[] = {
            (void*)&z_emb, (void*)&sample_h, (void*)&sample_c, (void*)&Wzp,
            (void*)&W_r, (void*)&memory, (void*)&keys, (void*)&h_all,
            (void*)&ctx_all, (void*)&bar
        };
        hipLaunchCooperativeKernel((const void*)recurrence_coop,
                                   dim3(NB * 4), dim3(1024), kargs, 0, stream);
    }

    attn_kernel<<<(NB * NT) / 8, 256, 0, stream>>>(h_all, ctx_all, W_attn,
                                                   attn_all, Ahl);

    if (use_mfma) {
        out_gemm_mfma<<<(NV / 128) * ((NB * NT) / 128), 256, 0, stream>>>(
            Ahl, Bt, b_fc, out);
    } else {
        out_gemm<<<dim3(NV / BN, (NB * NT) / BM), 256, 0, stream>>>(
            attn_all, W_fc, b_fc, out);
    }
}